// Round 2
// baseline (924.741 us; speedup 1.0000x reference)
//
#include <hip/hip_runtime.h>
#include <hip/hip_fp16.h>

typedef _Float16 f16;
typedef _Float16 f16x4 __attribute__((ext_vector_type(4)));
typedef _Float16 f16x8 __attribute__((ext_vector_type(8)));
typedef float f32x4 __attribute__((ext_vector_type(4)));
typedef float f32x16 __attribute__((ext_vector_type(16)));

static constexpr int CB = 8;      // batch
static constexpr int CC = 256;    // channels = Co
static constexpr int CN = 4096;   // tokens = H*W
static constexpr float LOG2E = 1.44269504088896f;

#define MFMA(a, b, c)   __builtin_amdgcn_mfma_f32_16x16x32_f16((a), (b), (c), 0, 0, 0)
#define MFMA32(a, b, c) __builtin_amdgcn_mfma_f32_32x32x16_f16((a), (b), (c), 0, 0, 0)

__device__ __forceinline__ void gll16(const void* g, void* l) {
  __builtin_amdgcn_global_load_lds(
      (const __attribute__((address_space(1))) unsigned int*)g,
      (__attribute__((address_space(3))) unsigned int*)l, 16, 0, 0);
}

__global__ __launch_bounds__(256) void prep_weights(const float* __restrict__ wq,
    const float* __restrict__ wk, const float* __restrict__ wv,
    const float* __restrict__ wo, f16* __restrict__ W) {
  int i = blockIdx.x * 256 + threadIdx.x;
  W[i]          = (f16)wq[i];
  W[65536 + i]  = (f16)wk[i];
  W[131072 + i] = (f16)wv[i];
  W[196608 + i] = (f16)wo[i];
}

// x [B,C,N] fp32  ->  Q,K [B,N,256] f16 ; V^T [B,256,N] f16   (unchanged, verified)
__global__ __launch_bounds__(256) void qkv_kernel(const float* __restrict__ x,
    const f16* __restrict__ Wq, const f16* __restrict__ Wk, const f16* __restrict__ Wv,
    const float* __restrict__ bq, const float* __restrict__ bk, const float* __restrict__ bv,
    f16* __restrict__ Q, f16* __restrict__ K, f16* __restrict__ Vt) {
  __shared__ f16 xf[64][264];
  const int b  = blockIdx.x >> 6;
  const int n0 = (blockIdx.x & 63) << 6;
  const int t  = threadIdx.x;
  const float* xb = x + (size_t)b * CC * CN;
  {
    int c = t >> 4;
    const int nn = (t & 15) << 2;
    #pragma unroll
    for (int pass = 0; pass < 16; ++pass, c += 16) {
      const float4 v = *(const float4*)(xb + (size_t)c * CN + n0 + nn);
      xf[nn + 0][c] = (f16)v.x;
      xf[nn + 1][c] = (f16)v.y;
      xf[nn + 2][c] = (f16)v.z;
      xf[nn + 3][c] = (f16)v.w;
    }
  }
  __syncthreads();
  const int w = t >> 6, l = t & 63, lr = l & 15, lh = l >> 4;

  f16x8 xff[8];
  #pragma unroll
  for (int kk = 0; kk < 8; ++kk)
    xff[kk] = *(const f16x8*)&xf[w * 16 + lr][kk * 32 + lh * 8];

  const size_t qkrow = ((size_t)b * CN + n0 + w * 16 + lr) * CC;

  #pragma unroll 1
  for (int mat = 0; mat < 2; ++mat) {
    const f16* W = mat ? Wk : Wq;
    const float* bias = mat ? bk : bq;
    f16* dst = mat ? K : Q;
    f32x4 acc[16];
    #pragma unroll
    for (int m = 0; m < 16; ++m) acc[m] = f32x4{0.f, 0.f, 0.f, 0.f};
    #pragma unroll
    for (int kk = 0; kk < 8; ++kk) {
      #pragma unroll
      for (int m = 0; m < 16; ++m) {
        f16x8 af = *(const f16x8*)&W[(size_t)(m * 16 + lr) * CC + kk * 32 + lh * 8];
        acc[m] = MFMA(af, xff[kk], acc[m]);
      }
    }
    #pragma unroll
    for (int m = 0; m < 16; ++m) {
      const int o = m * 16 + lh * 4;
      const float4 bs = *(const float4*)&bias[o];
      f16x4 hv;
      hv[0] = (f16)(acc[m][0] + bs.x);
      hv[1] = (f16)(acc[m][1] + bs.y);
      hv[2] = (f16)(acc[m][2] + bs.z);
      hv[3] = (f16)(acc[m][3] + bs.w);
      *(f16x4*)&dst[qkrow + o] = hv;
    }
  }
  {
    f32x4 acc[16];
    #pragma unroll
    for (int m = 0; m < 16; ++m) acc[m] = f32x4{0.f, 0.f, 0.f, 0.f};
    #pragma unroll
    for (int kk = 0; kk < 8; ++kk) {
      #pragma unroll
      for (int m = 0; m < 16; ++m) {
        f16x8 bf = *(const f16x8*)&Wv[(size_t)(m * 16 + lr) * CC + kk * 32 + lh * 8];
        acc[m] = MFMA(xff[kk], bf, acc[m]);
      }
    }
    #pragma unroll
    for (int m = 0; m < 16; ++m) {
      const int o = m * 16 + lr;
      const float bvs = bv[o];
      f16x4 hv;
      #pragma unroll
      for (int j = 0; j < 4; ++j) hv[j] = (f16)(acc[m][j] + bvs);
      *(f16x4*)&Vt[((size_t)b * CC + o) * CN + n0 + w * 16 + lh * 4] = hv;
    }
  }
}

// flash attention v2: 32x32x16 MFMA, 8 waves = 4 q-groups x 2 kv-halves,
// fragment-linear LDS frames staged via global_load_lds, block-local combine.
// Q,K [B,N,256], V^T [B,256,N] -> O [B,N,256]
__global__ __launch_bounds__(512, 2) void attn_kernel(const f16* __restrict__ Q,
    const f16* __restrict__ K, const f16* __restrict__ Vt, f16* __restrict__ O) {
  // SMEM layout (bytes):
  //   [0,      65536): Kf frames: ((hv*2+buf)*16 + ks)*1024, frag-linear (lane*16)
  //   [65536, 131072): Vf frames: ((hv*2+buf)*16 + f )*1024
  //   [131072,151552): Pl: per-wave 32 rows x 80B
  //   [151552,153600): alpha (loop) / m,l (epilogue)  -- time-disjoint uses
  //   epilogue: [0,131072) reused as Ox[8][32][128] f32
  __shared__ __align__(16) char SMEM[153600];

  const int bid = blockIdx.x;
  const int lb = ((bid & 7) << 5) | (bid >> 3);   // XCD swizzle: batch -> XCD
  const int b  = lb >> 5;
  const int q0 = (lb & 31) << 7;                  // 128 q-rows per block
  const int t  = threadIdx.x;
  const int w  = t >> 6, l = t & 63, ln = l & 31, lh = l >> 5;
  const int g  = w >> 1, hv = w & 1;              // q-group, kv-half

  const f16* Qb = Q  + (size_t)b * CN * CC;
  const f16* Kb = K  + (size_t)b * CN * CC;
  const f16* Vb = Vt + (size_t)b * CC * CN;

  auto kfr = [&](int buf, int ks) -> char* { return SMEM + (((hv * 2 + buf) * 16 + ks) << 10); };
  auto vfr = [&](int buf, int f)  -> char* { return SMEM + 65536 + (((hv * 2 + buf) * 16 + f) << 10); };
  char*  const PB = SMEM + 131072 + w * 2560;
  float* const AL = (float*)(SMEM + 151552) + w * 32;

  // stage one 32-kv tile (this wave's 4 K-frags + 4 V-frags, frag-linear)
  auto stage = [&](int buf, int kv0) {
    #pragma unroll
    for (int j = 0; j < 4; ++j) {
      const int ks = 4 * g + j;
      gll16(Kb + (size_t)(kv0 + ln) * CC + ks * 16 + 8 * lh, kfr(buf, ks));
    }
    #pragma unroll
    for (int j = 0; j < 4; ++j) {
      const int f = 4 * g + j;
      gll16(Vb + (size_t)((f >> 1) * 32 + ln) * CN + kv0 + (f & 1) * 16 + 8 * lh, vfr(buf, f));
    }
  };

  // Q fragments in registers: B-operand of swapped QK^T (lane: q=ln, c=16ks+8lh+e)
  const int qrow = q0 + 32 * g + ln;
  f16x8 qf[16];
  #pragma unroll
  for (int ks = 0; ks < 16; ++ks)
    qf[ks] = *(const f16x8*)(Qb + (size_t)qrow * CC + ks * 16 + 8 * lh);

  f32x16 oacc[8];
  #pragma unroll
  for (int ot = 0; ot < 8; ++ot)
    #pragma unroll
    for (int i = 0; i < 16; ++i) oacc[ot][i] = 0.0f;
  float mrun = -3e38f, lrun = 0.0f;

  const int kvb = hv * 2048;
  stage(0, kvb);
  __syncthreads();

  for (int it = 0; it < 64; ++it) {
    const int cur = it & 1;
    if (it < 63) stage(cur ^ 1, kvb + (it + 1) * 32);   // async prefetch, drained at barrier

    // swapped QK^T: S^T[kv][q] = K-tile x Q^T, A=K (lane: kv=ln), B=Q (lane: q=ln)
    f32x16 s;
    #pragma unroll
    for (int i = 0; i < 16; ++i) s[i] = 0.0f;
    #pragma unroll
    for (int ks = 0; ks < 16; ++ks) {
      const f16x8 kf = *(const f16x8*)(kfr(cur, ks) + l * 16);
      s = MFMA32(kf, qf[ks], s);
    }

    // online softmax: lane owns q=ln, 16 kv in-lane + partner (l^32) has other 16
    float pmax = -3e38f;
    #pragma unroll
    for (int r = 0; r < 16; ++r) pmax = fmaxf(pmax, s[r]);
    pmax = fmaxf(pmax, __shfl_xor(pmax, 32));
    const bool need = !__all(pmax - mrun <= 8.0f);      // defer-max (T13)
    float mnew = mrun;
    if (need) mnew = fmaxf(mrun, pmax);
    float psum = 0.0f;
    f16 pc[16];
    #pragma unroll
    for (int r = 0; r < 16; ++r) {
      const float p = exp2f((s[r] - mnew) * LOG2E);
      psum += p;
      pc[r] = (f16)p;
    }
    psum += __shfl_xor(psum, 32);
    if (need) {
      const float alpha = exp2f((mrun - mnew) * LOG2E);
      lrun = lrun * alpha + psum;
      mrun = mnew;
      if (l < 32) AL[l] = alpha;                        // lanes l and l^32 agree
      #pragma unroll
      for (int r = 0; r < 16; ++r) {
        const float fr = AL[(r & 3) + 8 * (r >> 2) + 4 * lh];  // alpha of row q(r)
        #pragma unroll
        for (int ot = 0; ot < 8; ++ot) oacc[ot][r] *= fr;
      }
    } else {
      lrun += psum;
    }

    // P relayout (wave-private): row q=ln, kv linear; 80B rows -> even bank use
    #pragma unroll
    for (int rg = 0; rg < 4; ++rg) {
      f16x4 pv = { pc[4 * rg], pc[4 * rg + 1], pc[4 * rg + 2], pc[4 * rg + 3] };
      *(f16x4*)(PB + 80 * ln + 16 * rg + 8 * lh) = pv;  // kv base = 8rg+4lh
    }
    const f16x8 pa0 = *(const f16x8*)(PB + 80 * ln + 16 * lh);        // kv 0..15
    const f16x8 pa1 = *(const f16x8*)(PB + 80 * ln + 32 + 16 * lh);   // kv 16..31

    // PV: out[q][o] += P x V ; B=V (lane: o=ln, kv=8lh+e) frag-linear reads
    #pragma unroll
    for (int ot = 0; ot < 8; ++ot) {
      const f16x8 v0 = *(const f16x8*)(vfr(cur, ot * 2) + l * 16);
      oacc[ot] = MFMA32(pa0, v0, oacc[ot]);
      const f16x8 v1 = *(const f16x8*)(vfr(cur, ot * 2 + 1) + l * 16);
      oacc[ot] = MFMA32(pa1, v1, oacc[ot]);
    }
    __syncthreads();
  }

  // block-local combine of the two kv-halves, through LDS
  float* const ML = (float*)(SMEM + 151552) + w * 64;
  if (l < 32) { ML[l] = mrun; ML[32 + l] = lrun; }
  float* const OxW = (float*)SMEM + w * 4096;           // 32q x 128o f32
  #pragma unroll
  for (int oi = 0; oi < 4; ++oi) {
    const int ot = hv ? oi : 4 + oi;                    // write partner's output tiles
    #pragma unroll
    for (int r = 0; r < 16; ++r) {
      const int q = (r & 3) + 8 * (r >> 2) + 4 * lh;
      OxW[q * 128 + oi * 32 + ln] = oacc[ot][r];
    }
  }
  __syncthreads();
  const int wp = w ^ 1;
  const float* OxP = (const float*)SMEM + wp * 4096;
  const float* MLp = (const float*)(SMEM + 151552) + wp * 64;
  f16* Ob = O + ((size_t)b * CN + q0 + 32 * g) * CC + hv * 128;
  #pragma unroll
  for (int r = 0; r < 16; ++r) {
    const int q = (r & 3) + 8 * (r >> 2) + 4 * lh;
    const float ma = ML[q],  la  = ML[32 + q];
    const float mb = MLp[q], lb_ = MLp[32 + q];
    const float mm = fmaxf(ma, mb);
    const float ca = exp2f((ma - mm) * LOG2E), cb = exp2f((mb - mm) * LOG2E);
    const float inv = 1.0f / (ca * la + cb * lb_);
    #pragma unroll
    for (int oi = 0; oi < 4; ++oi) {
      const int ot = hv ? 4 + oi : oi;                  // own kept tiles
      const float comb = (ca * oacc[ot][r] + cb * OxP[q * 128 + oi * 32 + ln]) * inv;
      Ob[(size_t)q * CC + oi * 32 + ln] = (f16)comb;
    }
  }
}

// out[b,c,n] = sum_o O[b,n,o] * Wo[c,o] + bo[c]   (unchanged, verified)
__global__ __launch_bounds__(256) void oproj_kernel(const f16* __restrict__ O,
    const f16* __restrict__ Wo, const float* __restrict__ bo, float* __restrict__ out) {
  const int b  = blockIdx.x >> 6;
  const int n0 = (blockIdx.x & 63) << 6;
  const int t  = threadIdx.x;
  const int w = t >> 6, l = t & 63, lr = l & 15, lh = l >> 4;
  const f16* orow = O + ((size_t)b * CN + n0 + w * 16 + lr) * CC;
  f32x4 acc[16];
  #pragma unroll
  for (int m = 0; m < 16; ++m) acc[m] = f32x4{0.f, 0.f, 0.f, 0.f};
  #pragma unroll
  for (int kk = 0; kk < 8; ++kk) {
    const f16x8 bf = *(const f16x8*)&orow[kk * 32 + lh * 8];
    #pragma unroll
    for (int m = 0; m < 16; ++m) {
      f16x8 af = *(const f16x8*)&Wo[(size_t)(m * 16 + lr) * CC + kk * 32 + lh * 8];
      acc[m] = MFMA(af, bf, acc[m]);
    }
  }
  #pragma unroll
  for (int m = 0; m < 16; ++m) {
    const int c = m * 16 + lh * 4;
    const float4 bv4 = *(const float4*)&bo[c];
    const size_t base = ((size_t)b * CC + c) * CN + n0 + w * 16 + lr;
    out[base + 0 * (size_t)CN] = acc[m][0] + bv4.x;
    out[base + 1 * (size_t)CN] = acc[m][1] + bv4.y;
    out[base + 2 * (size_t)CN] = acc[m][2] + bv4.z;
    out[base + 3 * (size_t)CN] = acc[m][3] + bv4.w;
  }
}

extern "C" void kernel_launch(void* const* d_in, const int* in_sizes, int n_in,
                              void* d_out, int out_size, void* d_ws, size_t ws_size,
                              hipStream_t stream) {
  const float* x  = (const float*)d_in[0];
  const float* wq = (const float*)d_in[1];
  const float* bq = (const float*)d_in[2];
  const float* wk = (const float*)d_in[3];
  const float* bk = (const float*)d_in[4];
  const float* wv = (const float*)d_in[5];
  const float* bv = (const float*)d_in[6];
  const float* wo = (const float*)d_in[7];
  const float* bo = (const float*)d_in[8];

  f16* W  = (f16*)d_ws;                     // 4 x 65536 f16 weights
  f16* Qd = W + 262144;                     // [B,N,256]
  f16* Kd = Qd + (size_t)CB * CN * CC;      // [B,N,256]
  f16* Vt = Kd + (size_t)CB * CN * CC;      // [B,256,N]
  f16* Od = Vt + (size_t)CB * CN * CC;      // [B,N,256]

  prep_weights<<<256, 256, 0, stream>>>(wq, wk, wv, wo, W);
  qkv_kernel<<<512, 256, 0, stream>>>(x, W, W + 65536, W + 131072, bq, bk, bv, Qd, Kd, Vt);
  attn_kernel<<<256, 512, 0, stream>>>(Qd, Kd, Vt, Od);
  oproj_kernel<<<512, 256, 0, stream>>>(Od, W + 196608, bo, (float*)d_out);
}

// Round 3
// 396.567 us; speedup vs baseline: 2.3319x; 2.3319x over previous
//
#include <hip/hip_runtime.h>
#include <hip/hip_fp16.h>

typedef _Float16 f16;
typedef _Float16 f16x4 __attribute__((ext_vector_type(4)));
typedef _Float16 f16x8 __attribute__((ext_vector_type(8)));
typedef float f32x4 __attribute__((ext_vector_type(4)));
typedef float f32x16 __attribute__((ext_vector_type(16)));

static constexpr int CB = 8;      // batch
static constexpr int CC = 256;    // channels = Co
static constexpr int CN = 4096;   // tokens = H*W
static constexpr float LOG2E = 1.44269504088896f;

#define MFMA(a, b, c)   __builtin_amdgcn_mfma_f32_16x16x32_f16((a), (b), (c), 0, 0, 0)
#define MFMA32(a, b, c) __builtin_amdgcn_mfma_f32_32x32x16_f16((a), (b), (c), 0, 0, 0)

__device__ __forceinline__ void gll16(const void* g, void* l) {
  __builtin_amdgcn_global_load_lds(
      (const __attribute__((address_space(1))) unsigned int*)g,
      (__attribute__((address_space(3))) unsigned int*)l, 16, 0, 0);
}

__global__ __launch_bounds__(256) void prep_weights(const float* __restrict__ wq,
    const float* __restrict__ wk, const float* __restrict__ wv,
    const float* __restrict__ wo, f16* __restrict__ W) {
  int i = blockIdx.x * 256 + threadIdx.x;
  W[i]          = (f16)wq[i];
  W[65536 + i]  = (f16)wk[i];
  W[131072 + i] = (f16)wv[i];
  W[196608 + i] = (f16)wo[i];
}

// x [B,C,N] fp32  ->  Q,K [B,N,256] f16 ; V^T [B,256,N] f16   (unchanged, verified)
__global__ __launch_bounds__(256) void qkv_kernel(const float* __restrict__ x,
    const f16* __restrict__ Wq, const f16* __restrict__ Wk, const f16* __restrict__ Wv,
    const float* __restrict__ bq, const float* __restrict__ bk, const float* __restrict__ bv,
    f16* __restrict__ Q, f16* __restrict__ K, f16* __restrict__ Vt) {
  __shared__ f16 xf[64][264];
  const int b  = blockIdx.x >> 6;
  const int n0 = (blockIdx.x & 63) << 6;
  const int t  = threadIdx.x;
  const float* xb = x + (size_t)b * CC * CN;
  {
    int c = t >> 4;
    const int nn = (t & 15) << 2;
    #pragma unroll
    for (int pass = 0; pass < 16; ++pass, c += 16) {
      const float4 v = *(const float4*)(xb + (size_t)c * CN + n0 + nn);
      xf[nn + 0][c] = (f16)v.x;
      xf[nn + 1][c] = (f16)v.y;
      xf[nn + 2][c] = (f16)v.z;
      xf[nn + 3][c] = (f16)v.w;
    }
  }
  __syncthreads();
  const int w = t >> 6, l = t & 63, lr = l & 15, lh = l >> 4;

  f16x8 xff[8];
  #pragma unroll
  for (int kk = 0; kk < 8; ++kk)
    xff[kk] = *(const f16x8*)&xf[w * 16 + lr][kk * 32 + lh * 8];

  const size_t qkrow = ((size_t)b * CN + n0 + w * 16 + lr) * CC;

  #pragma unroll 1
  for (int mat = 0; mat < 2; ++mat) {
    const f16* W = mat ? Wk : Wq;
    const float* bias = mat ? bk : bq;
    f16* dst = mat ? K : Q;
    f32x4 acc[16];
    #pragma unroll
    for (int m = 0; m < 16; ++m) acc[m] = f32x4{0.f, 0.f, 0.f, 0.f};
    #pragma unroll
    for (int kk = 0; kk < 8; ++kk) {
      #pragma unroll
      for (int m = 0; m < 16; ++m) {
        f16x8 af = *(const f16x8*)&W[(size_t)(m * 16 + lr) * CC + kk * 32 + lh * 8];
        acc[m] = MFMA(af, xff[kk], acc[m]);
      }
    }
    #pragma unroll
    for (int m = 0; m < 16; ++m) {
      const int o = m * 16 + lh * 4;
      const float4 bs = *(const float4*)&bias[o];
      f16x4 hv;
      hv[0] = (f16)(acc[m][0] + bs.x);
      hv[1] = (f16)(acc[m][1] + bs.y);
      hv[2] = (f16)(acc[m][2] + bs.z);
      hv[3] = (f16)(acc[m][3] + bs.w);
      *(f16x4*)&dst[qkrow + o] = hv;
    }
  }
  {
    f32x4 acc[16];
    #pragma unroll
    for (int m = 0; m < 16; ++m) acc[m] = f32x4{0.f, 0.f, 0.f, 0.f};
    #pragma unroll
    for (int kk = 0; kk < 8; ++kk) {
      #pragma unroll
      for (int m = 0; m < 16; ++m) {
        f16x8 bf = *(const f16x8*)&Wv[(size_t)(m * 16 + lr) * CC + kk * 32 + lh * 8];
        acc[m] = MFMA(xff[kk], bf, acc[m]);
      }
    }
    #pragma unroll
    for (int m = 0; m < 16; ++m) {
      const int o = m * 16 + lr;
      const float bvs = bv[o];
      f16x4 hv;
      #pragma unroll
      for (int j = 0; j < 4; ++j) hv[j] = (f16)(acc[m][j] + bvs);
      *(f16x4*)&Vt[((size_t)b * CC + o) * CN + n0 + w * 16 + lh * 4] = hv;
    }
  }
}

// flash attention v3: 32x32x16 MFMA, 8 waves = 4 q-groups x 2 o-halves,
// full kv sweep per wave (no combine), shared frag-linear K/V frames via
// global_load_lds, Q in registers, defer-max online softmax.
// Q,K [B,N,256], V^T [B,256,N] -> O [B,N,256]
__global__ __launch_bounds__(512, 2) void attn_kernel(const f16* __restrict__ Q,
    const f16* __restrict__ K, const f16* __restrict__ Vt, f16* __restrict__ O) {
  // SMEM (bytes):
  //   [0, 65536):     K/V frames: buf*32768 + frame*1024; frame 0..15 = K(ks),
  //                   16..31 = V(j). All frag-linear: lane l at +16*l.
  //   [65536, 88064): P relayout: wave w at +w*2816, 32 rows x 88 B (2-way banks)
  //   [88064, 89088): per-wave alpha/inv floats: w*128
  __shared__ __align__(16) char SMEM[89088];

  const int bid = blockIdx.x;
  const int lb = ((bid & 7) << 5) | (bid >> 3);   // XCD swizzle: batch -> XCD
  const int b  = lb >> 5;
  const int q0 = (lb & 31) << 7;                  // 128 q-rows per block
  const int t  = threadIdx.x;
  const int w  = t >> 6, l = t & 63, ln = l & 31, lh = l >> 5;
  const int g  = w >> 1, hv = w & 1;              // q-group, o-half

  const f16* Qb = Q  + (size_t)b * CN * CC;
  const f16* Kb = K  + (size_t)b * CN * CC;
  const f16* Vb = Vt + (size_t)b * CC * CN;

  float* const ALf = (float*)(SMEM + 88064 + w * 128);
  char*  const PB  = SMEM + 65536 + w * 2816;

  // stage one 32-kv tile: waves 0-3 stage K frames 4w..4w+3, waves 4-7 stage V
  auto stage = [&](int buf, int kv0) {
    char* base = SMEM + (buf << 15);
    if (w < 4) {
      const f16* src = Kb + (size_t)(kv0 + ln) * CC + (w * 4) * 16 + 8 * lh;
      #pragma unroll
      for (int j = 0; j < 4; ++j)
        gll16(src + j * 16, base + ((w * 4 + j) << 10));
    } else {
      const int j0 = (w - 4) * 4;
      #pragma unroll
      for (int p = 0; p < 2; ++p) {
        const f16* src = Vb + (size_t)(((j0 >> 1) + p) * 32 + ln) * CN + kv0 + 8 * lh;
        gll16(src,      base + ((16 + j0 + 2 * p)     << 10));
        gll16(src + 16, base + ((16 + j0 + 2 * p + 1) << 10));
      }
    }
  };

  // Q fragments in registers: B-operand of swapped QK^T (lane: q=ln, c=16ks+8lh+e)
  const int qrow = q0 + 32 * g + ln;
  f16x8 qf[16];
  #pragma unroll
  for (int ks = 0; ks < 16; ++ks)
    qf[ks] = *(const f16x8*)(Qb + (size_t)qrow * CC + ks * 16 + 8 * lh);

  f32x16 oacc[4];
  #pragma unroll
  for (int ot = 0; ot < 4; ++ot)
    #pragma unroll
    for (int i = 0; i < 16; ++i) oacc[ot][i] = 0.0f;
  float mrun = -3e38f, lrun = 0.0f;

  stage(0, 0);
  __syncthreads();

  for (int it = 0; it < 128; ++it) {
    const int cur = it & 1;
    if (it < 127) stage(cur ^ 1, (it + 1) * 32);   // async prefetch, drained at barrier

    // swapped QK^T: S^T[kv][q]; A=K frag (lane: kv=ln, c=16ks+8lh+e), B=Q frag
    f32x16 s;
    #pragma unroll
    for (int i = 0; i < 16; ++i) s[i] = 0.0f;
    #pragma unroll
    for (int ks = 0; ks < 16; ++ks) {
      const f16x8 kf = *(const f16x8*)(SMEM + (cur << 15) + (ks << 10) + l * 16);
      s = MFMA32(kf, qf[ks], s);
    }

    // online softmax: lane owns q=ln; 16 kv in-lane, partner (l^32) has other 16
    float pmax = -3e38f;
    #pragma unroll
    for (int r = 0; r < 16; ++r) pmax = fmaxf(pmax, s[r]);
    pmax = fmaxf(pmax, __shfl_xor(pmax, 32));
    const bool need = !__all(pmax - mrun <= 8.0f);      // defer-max (T13)
    float mnew = mrun;
    if (need) mnew = fmaxf(mrun, pmax);
    float psum = 0.0f;
    f16 pc[16];
    #pragma unroll
    for (int r = 0; r < 16; ++r) {
      const float p = exp2f((s[r] - mnew) * LOG2E);
      psum += p;
      pc[r] = (f16)p;
    }
    psum += __shfl_xor(psum, 32);
    if (need) {                                          // rare rescale path
      const float alpha = exp2f((mrun - mnew) * LOG2E);
      lrun = lrun * alpha + psum;
      mrun = mnew;
      if (l < 32) ALf[ln] = alpha;                       // lanes l, l^32 agree
      #pragma unroll
      for (int r = 0; r < 16; ++r) {
        const float fr = ALf[(r & 3) + 8 * (r >> 2) + 4 * lh];  // alpha of q(r)
        #pragma unroll
        for (int ot = 0; ot < 4; ++ot) oacc[ot][r] *= fr;
      }
    } else {
      lrun += psum;
    }

    // P relayout (wave-private): row q=ln (88 B stride), kv-linear within row
    #pragma unroll
    for (int rg = 0; rg < 4; ++rg) {
      f16x4 pv = { pc[4 * rg], pc[4 * rg + 1], pc[4 * rg + 2], pc[4 * rg + 3] };
      *(f16x4*)(PB + 88 * ln + 16 * rg + 8 * lh) = pv;   // kv = 8rg + 4lh + j
    }
    const f16x8 pa0 = *(const f16x8*)(PB + 88 * ln + 16 * lh);        // kv 0..15
    const f16x8 pa1 = *(const f16x8*)(PB + 88 * ln + 32 + 16 * lh);   // kv 16..31

    // PV: D[q][o] += P x V; B=V frag (lane: o=ln, kv=8lh+e); own o-half only
    #pragma unroll
    for (int ot = 0; ot < 4; ++ot) {
      const int f0 = 16 + 8 * hv + 2 * ot;
      const f16x8 v0 = *(const f16x8*)(SMEM + (cur << 15) + (f0 << 10) + l * 16);
      oacc[ot] = MFMA32(pa0, v0, oacc[ot]);
      const f16x8 v1 = *(const f16x8*)(SMEM + (cur << 15) + ((f0 + 1) << 10) + l * 16);
      oacc[ot] = MFMA32(pa1, v1, oacc[ot]);
    }
    __syncthreads();
  }

  // epilogue: direct store of own 32q x 128o slice, scaled by 1/l
  if (l < 32) ALf[ln] = 1.0f / lrun;
  f16* Ob = O + ((size_t)b * CN + q0 + 32 * g) * CC + 128 * hv;
  #pragma unroll
  for (int r = 0; r < 16; ++r) {
    const int q = (r & 3) + 8 * (r >> 2) + 4 * lh;
    const float inv = ALf[q];
    #pragma unroll
    for (int ot = 0; ot < 4; ++ot)
      Ob[(size_t)q * CC + ot * 32 + ln] = (f16)(oacc[ot][r] * inv);
  }
}

// out[b,c,n] = sum_o O[b,n,o] * Wo[c,o] + bo[c]   (unchanged, verified)
__global__ __launch_bounds__(256) void oproj_kernel(const f16* __restrict__ O,
    const f16* __restrict__ Wo, const float* __restrict__ bo, float* __restrict__ out) {
  const int b  = blockIdx.x >> 6;
  const int n0 = (blockIdx.x & 63) << 6;
  const int t  = threadIdx.x;
  const int w = t >> 6, l = t & 63, lr = l & 15, lh = l >> 4;
  const f16* orow = O + ((size_t)b * CN + n0 + w * 16 + lr) * CC;
  f32x4 acc[16];
  #pragma unroll
  for (int m = 0; m < 16; ++m) acc[m] = f32x4{0.f, 0.f, 0.f, 0.f};
  #pragma unroll
  for (int kk = 0; kk < 8; ++kk) {
    const f16x8 bf = *(const f16x8*)&orow[kk * 32 + lh * 8];
    #pragma unroll
    for (int m = 0; m < 16; ++m) {
      f16x8 af = *(const f16x8*)&Wo[(size_t)(m * 16 + lr) * CC + kk * 32 + lh * 8];
      acc[m] = MFMA(af, bf, acc[m]);
    }
  }
  #pragma unroll
  for (int m = 0; m < 16; ++m) {
    const int c = m * 16 + lh * 4;
    const float4 bv4 = *(const float4*)&bo[c];
    const size_t base = ((size_t)b * CC + c) * CN + n0 + w * 16 + lr;
    out[base + 0 * (size_t)CN] = acc[m][0] + bv4.x;
    out[base + 1 * (size_t)CN] = acc[m][1] + bv4.y;
    out[base + 2 * (size_t)CN] = acc[m][2] + bv4.z;
    out[base + 3 * (size_t)CN] = acc[m][3] + bv4.w;
  }
}

extern "C" void kernel_launch(void* const* d_in, const int* in_sizes, int n_in,
                              void* d_out, int out_size, void* d_ws, size_t ws_size,
                              hipStream_t stream) {
  const float* x  = (const float*)d_in[0];
  const float* wq = (const float*)d_in[1];
  const float* bq = (const float*)d_in[2];
  const float* wk = (const float*)d_in[3];
  const float* bk = (const float*)d_in[4];
  const float* wv = (const float*)d_in[5];
  const float* bv = (const float*)d_in[6];
  const float* wo = (const float*)d_in[7];
  const float* bo = (const float*)d_in[8];

  f16* W  = (f16*)d_ws;                     // 4 x 65536 f16 weights
  f16* Qd = W + 262144;                     // [B,N,256]
  f16* Kd = Qd + (size_t)CB * CN * CC;      // [B,N,256]
  f16* Vt = Kd + (size_t)CB * CN * CC;      // [B,256,N]
  f16* Od = Vt + (size_t)CB * CN * CC;      // [B,N,256]

  prep_weights<<<256, 256, 0, stream>>>(wq, wk, wv, wo, W);
  qkv_kernel<<<512, 256, 0, stream>>>(x, W, W + 65536, W + 131072, bq, bk, bv, Qd, Kd, Vt);
  attn_kernel<<<256, 512, 0, stream>>>(Qd, Kd, Vt, Od);
  oproj_kernel<<<512, 256, 0, stream>>>(Od, W + 196608, bo, (float*)d_out);
}